// Round 3
// baseline (544.421 us; speedup 1.0000x reference)
//
#include <hip/hip_runtime.h>

#define BB 256
#define NPER 512
#define FF 256
#define DD 32
#define EE 524288
#define NN (BB*NPER)          // 131072
#define NSTEPS 4

__device__ __forceinline__ float bflo(unsigned u) { return __uint_as_float(u << 16); }
__device__ __forceinline__ float bfhi(unsigned u) { return __uint_as_float(u & 0xFFFF0000u); }
__device__ __forceinline__ unsigned rtn_bf16(unsigned u) {
    return (u + 0x7FFFu + ((u >> 16) & 1u)) >> 16;
}

// ---------------- one-time kernels ----------------

__global__ void k_degpack(const int* __restrict__ dst, unsigned* __restrict__ deg,
                          const float* __restrict__ xs0, const float* __restrict__ q,
                          float2* __restrict__ xq) {
    int t = blockIdx.x * blockDim.x + threadIdx.x;
    if (t < NN) { float2 v; v.x = xs0[t]; v.y = q[t]; xq[t] = v; }
    atomicAdd(&deg[dst[t]], 1u);
}

__global__ void k_bsum(const unsigned* __restrict__ deg, unsigned* __restrict__ bsum) {
    __shared__ unsigned r[256];
    int t = threadIdx.x;
    r[t] = deg[blockIdx.x * 256 + t];
    __syncthreads();
    for (int o = 128; o > 0; o >>= 1) { if (t < o) r[t] += r[t + o]; __syncthreads(); }
    if (t == 0) bsum[blockIdx.x] = r[0];
}

__global__ void k_scanb(const unsigned* __restrict__ bsum, unsigned* __restrict__ bbase) {
    __shared__ unsigned r[512];
    int t = threadIdx.x;
    unsigned own = bsum[t];
    r[t] = own;
    __syncthreads();
    for (int o = 1; o < 512; o <<= 1) {
        unsigned v = (t >= o) ? r[t - o] : 0u;
        __syncthreads();
        r[t] += v;
        __syncthreads();
    }
    bbase[t] = r[t] - own;
}

__global__ void k_offsets(const unsigned* __restrict__ deg, const unsigned* __restrict__ bbase,
                          unsigned* __restrict__ rowstart, unsigned* __restrict__ cursor) {
    __shared__ unsigned r[256];
    int t = threadIdx.x;
    int i = blockIdx.x * 256 + t;
    unsigned d = deg[i];
    r[t] = d;
    __syncthreads();
    for (int o = 1; o < 256; o <<= 1) {
        unsigned v = (t >= o) ? r[t - o] : 0u;
        __syncthreads();
        r[t] += v;
        __syncthreads();
    }
    unsigned excl = r[t] - d + bbase[blockIdx.x];
    rowstart[i] = excl;
    cursor[i] = excl;
}

__global__ void k_fill(const int* __restrict__ src, const int* __restrict__ dst,
                       unsigned* __restrict__ cursor, int* __restrict__ csr_src) {
    int e = blockIdx.x * blockDim.x + threadIdx.x;
    unsigned pos = atomicAdd(&cursor[dst[e]], 1u);
    csr_src[pos] = src[e];
}

// one-time fp32 -> bf16 cast of P (pure streaming, 8 floats/thread)
__global__ __launch_bounds__(256) void k_cast(const float* __restrict__ Pf,
                                              unsigned short* __restrict__ Pbf) {
    size_t idx = ((size_t)blockIdx.x * 256 + threadIdx.x) * 8;
    float4 a = *(const float4*)(Pf + idx);
    float4 c = *(const float4*)(Pf + idx + 4);
    uint4 o;
    o.x = rtn_bf16(__float_as_uint(a.x)) | (rtn_bf16(__float_as_uint(a.y)) << 16);
    o.y = rtn_bf16(__float_as_uint(a.z)) | (rtn_bf16(__float_as_uint(a.w)) << 16);
    o.z = rtn_bf16(__float_as_uint(c.x)) | (rtn_bf16(__float_as_uint(c.y)) << 16);
    o.w = rtn_bf16(__float_as_uint(c.z)) | (rtn_bf16(__float_as_uint(c.w)) << 16);
    *(uint4*)(Pbf + idx) = o;
}

// ---------------- per-step kernels ----------------

// fused gather + node MLP (unchanged)
__global__ void k_node_g(const float2* __restrict__ xq,
                         const float* __restrict__ Win, const float* __restrict__ bin,
                         const unsigned* __restrict__ rowstart, const unsigned* __restrict__ deg,
                         const int* __restrict__ csr_src,
                         const float* __restrict__ Wmsg, const float* __restrict__ bmsg,
                         const float* __restrict__ Wout, const float* __restrict__ bout,
                         float* __restrict__ pred, float* __restrict__ out_preds, int step) {
    int tid = threadIdx.x;                  // 256 = 8 nodes x 32 channels
    int d = tid & 31;
    int i = blockIdx.x * 8 + (tid >> 5);
    float w0 = Win[d], w1 = Win[DD + d], b0 = bin[d];
    float wcol[DD];
    #pragma unroll
    for (int k = 0; k < DD; ++k) wcol[k] = Wmsg[k * DD + d];
    unsigned rs = rowstart[i];
    unsigned dg = deg[i];
    unsigned nfull = dg < 32u ? dg : 32u;
    float xv = 0.f, qv = 0.f;
    if ((unsigned)d < nfull) {
        int sv = csr_src[rs + d];
        float2 v = xq[sv];
        xv = v.x; qv = v.y;
    }
    float s = 0.f;
    for (unsigned j = 0; j < nfull; ++j) {
        float xj = __shfl(xv, (int)j, 32);
        float qj = __shfl(qv, (int)j, 32);
        s += fmaxf(xj * w0 + qj * w1 + b0, 0.f);
    }
    for (unsigned j = 32; j < dg; ++j) {
        int sv = csr_src[rs + j];
        float2 v = xq[sv];
        s += fmaxf(v.x * w0 + v.y * w1 + b0, 0.f);
    }
    float2 self = xq[i];
    float hval = fmaxf(self.x * w0 + self.y * w1 + b0, 0.f);
    float agg = (float)dg * bmsg[d];
    #pragma unroll
    for (int k = 0; k < DD; ++k) agg += __shfl(s, k, 32) * wcol[k];
    float h2 = fmaxf(hval + agg, 0.f);
    float v = h2 * Wout[d];
    for (int o = 16; o > 0; o >>= 1) v += __shfl_down(v, o, 32);
    if (d == 0) {
        float pr = v + bout[0];
        pred[i] = pr;
        out_preds[i * NSTEPS + step] = pr;
    }
}

// projection step: ONE block per graph (block-local sync only, no co-residency
// assumptions). 1024 threads = 16 waves; wave w owns rows w*32..w*32+31, lane l
// owns channels 4l..4l+3. The graph's 256KB bf16 P-slab is held in registers
// (pl[64]) so pproj needs no second global read of P.
__global__ __launch_bounds__(1024) void k_proj(const unsigned short* __restrict__ Pbf,
                                               float2* __restrict__ xq,
                                               const float* __restrict__ xsol,
                                               const float* __restrict__ pred,
                                               float* __restrict__ out_labels,
                                               float tau, int step) {
    __shared__ float dd_l[NPER], x_l[NPER], pp_l[NPER];
    __shared__ float sl[16 * FF];
    __shared__ float dfl[FF];
    __shared__ float redA[16], redB[16], wmin[16];
    int b = blockIdx.x;
    int t = threadIdx.x;
    int w = t >> 6, lane = t & 63;
    int gbase = b * NPER;

    // --- Sr, Sp + labels + dd ---
    float x = 0.f, r = 0.f, p = 0.f, a1 = 0.f, a2 = 0.f;
    if (t < NPER) {
        x = xq[gbase + t].x;
        r = xsol[gbase + t] - x;
        p = pred[gbase + t];
        a1 = fabsf(r); a2 = fabsf(p);
    }
    #pragma unroll
    for (int o = 32; o > 0; o >>= 1) {
        a1 += __shfl_down(a1, o, 64);
        a2 += __shfl_down(a2, o, 64);
    }
    if (lane == 0) { redA[w] = a1; redB[w] = a2; }
    __syncthreads();
    float Sr = 1e-12f, Sp = 1e-12f;
    #pragma unroll
    for (int k = 0; k < 16; ++k) { Sr += redA[k]; Sp += redB[k]; }
    if (t < NPER) {
        out_labels[(size_t)(gbase + t) * NSTEPS + step] = r / Sr;
        x_l[t] = x;
        dd_l[t] = p / Sp + 3.0f * tau / (x + tau);
    }
    __syncthreads();

    // --- phase 1: stream P slab into registers; df partial ---
    size_t pbase = ((size_t)(gbase + w * 32)) * FF + 4 * lane;
    const uint2* Pr = (const uint2*)(Pbf + pbase);
    unsigned pl[64];                       // 32 rows x 2 packed-bf16 words
    #pragma unroll
    for (int n = 0; n < 32; ++n) {         // 32 independent loads in flight
        uint2 pv = Pr[(size_t)n * 64];     // row stride = 64 uint2 = FF bf16
        pl[2 * n] = pv.x; pl[2 * n + 1] = pv.y;
    }
    float4 acc = {0.f, 0.f, 0.f, 0.f};
    #pragma unroll
    for (int n = 0; n < 32; ++n) {
        float sc = dd_l[w * 32 + n];
        acc.x += bflo(pl[2 * n]) * sc;
        acc.y += bfhi(pl[2 * n]) * sc;
        acc.z += bflo(pl[2 * n + 1]) * sc;
        acc.w += bfhi(pl[2 * n + 1]) * sc;
    }
    ((float4*)sl)[w * 64 + lane] = acc;
    __syncthreads();
    if (t < FF) {
        float v = 0.f;
        #pragma unroll
        for (int k = 0; k < 16; ++k) v += sl[k * FF + t];
        dfl[t] = v;
    }
    __syncthreads();

    // --- phase 2: pproj from registers + line-search min ---
    float4 dfv = ((const float4*)dfl)[lane];
    float mloc = 5.0f;
    #pragma unroll
    for (int n = 0; n < 32; ++n) {
        float pr = bflo(pl[2 * n]) * dfv.x + bfhi(pl[2 * n]) * dfv.y
                 + bflo(pl[2 * n + 1]) * dfv.z + bfhi(pl[2 * n + 1]) * dfv.w;
        #pragma unroll
        for (int o = 1; o < 64; o <<= 1) pr += __shfl_xor(pr, o, 64);
        if (lane == 0) pp_l[w * 32 + n] = pr;
        float xr = x_l[w * 32 + n];
        float ratio = (pr < 0.f) ? (xr / fmaxf(-pr, 1e-12f)) : 5.0f;
        mloc = fminf(mloc, ratio);
    }
    if (lane == 0) wmin[w] = mloc;
    __syncthreads();

    // --- line-search min over waves + update ---
    float mm = wmin[0];
    #pragma unroll
    for (int k = 1; k < 16; ++k) mm = fminf(mm, wmin[k]);
    float alpha = fminf(fmaxf(mm, 0.f), 5.0f) * 0.995f;
    if (t < NPER) xq[gbase + t].x = x_l[t] + alpha * pp_l[t];
}

// last step: labels only
__global__ __launch_bounds__(512) void k_lab(const float2* __restrict__ xq,
                                             const float* __restrict__ xsol,
                                             float* __restrict__ out_labels, int step) {
    int b = blockIdx.x;
    int t = threadIdx.x;                 // 512 = 8 waves
    int w = t >> 6, lane = t & 63;
    int i = b * NPER + t;
    float x = xq[i].x;
    float r = xsol[i] - x;
    float a1 = fabsf(r);
    #pragma unroll
    for (int o = 32; o > 0; o >>= 1) a1 += __shfl_down(a1, o, 64);
    __shared__ float red[8];
    if (lane == 0) red[w] = a1;
    __syncthreads();
    float Sr = 1e-12f;
    #pragma unroll
    for (int k = 0; k < 8; ++k) Sr += red[k];
    out_labels[(size_t)i * NSTEPS + step] = r / Sr;
}

// ---------------- launch ----------------

extern "C" void kernel_launch(void* const* d_in, const int* in_sizes, int n_in,
                              void* d_out, int out_size, void* d_ws, size_t ws_size,
                              hipStream_t stream) {
    const float* x_start = (const float*)d_in[0];
    const float* x_sol   = (const float*)d_in[1];
    const float* q       = (const float*)d_in[2];
    const float* P       = (const float*)d_in[3];
    const float* Win     = (const float*)d_in[4];
    const float* bin     = (const float*)d_in[5];
    const float* Wmsg    = (const float*)d_in[6];
    const float* bmsg    = (const float*)d_in[7];
    const float* Wout    = (const float*)d_in[8];
    const float* bout    = (const float*)d_in[9];
    const int*   esrc    = (const int*)d_in[10];
    const int*   edst    = (const int*)d_in[11];
    // d_in[12] vals_batch unused: batch(i) == i >> 9 (equal-sized contiguous graphs)

    float* out_preds  = (float*)d_out;                // [N, 4] row-major
    float* out_labels = (float*)d_out + (size_t)NN * NSTEPS;

    float* w = (float*)d_ws;
    float2* xq  = (float2*)w; w += 2 * (size_t)NN;
    float* pred  = w; w += NN;
    unsigned* deg      = (unsigned*)w; w += NN;
    unsigned* rowstart = (unsigned*)w; w += NN;
    unsigned* cursor   = (unsigned*)w; w += NN;
    unsigned* bsum     = (unsigned*)w; w += NN / 256;   // 512
    unsigned* bbase    = (unsigned*)w; w += NN / 256;   // 512
    int* csr_src       = (int*)w;      w += EE;
    unsigned short* Pbf = (unsigned short*)w;           // 64 MB bf16 copy of P

    // --- one-time: CSR build + xq pack + bf16 cast of P
    hipMemsetAsync(deg, 0, NN * sizeof(unsigned), stream);
    k_degpack<<<EE / 256, 256, 0, stream>>>(edst, deg, x_start, q, xq);
    k_cast<<<(NN / 256) * (FF / 8), 256, 0, stream>>>(P, Pbf);   // 16384 blocks
    k_bsum<<<NN / 256, 256, 0, stream>>>(deg, bsum);
    k_scanb<<<1, NN / 256, 0, stream>>>(bsum, bbase);
    k_offsets<<<NN / 256, 256, 0, stream>>>(deg, bbase, rowstart, cursor);
    k_fill<<<EE / 256, 256, 0, stream>>>(esrc, edst, cursor, csr_src);

    float tau = 0.1f;
    for (int step = 0; step < NSTEPS; ++step) {
        k_node_g<<<NN / 8, 256, 0, stream>>>(xq, Win, bin, rowstart, deg, csr_src,
                                             Wmsg, bmsg, Wout, bout, pred, out_preds, step);
        if (step < NSTEPS - 1) {
            k_proj<<<BB, 1024, 0, stream>>>(Pbf, xq, x_sol, pred, out_labels, tau, step);
        } else {
            k_lab<<<BB, 512, 0, stream>>>(xq, x_sol, out_labels, step);
        }
        tau = fmaxf(tau * 0.5f, 1e-5f);
    }
}

// Round 4
// 525.437 us; speedup vs baseline: 1.0361x; 1.0361x over previous
//
#include <hip/hip_runtime.h>

#define BB 256
#define NPER 512
#define FF 256
#define DD 32
#define EE 524288
#define NN (BB*NPER)          // 131072
#define NSTEPS 4

__device__ __forceinline__ float bflo(unsigned u) { return __uint_as_float(u << 16); }
__device__ __forceinline__ float bfhi(unsigned u) { return __uint_as_float(u & 0xFFFF0000u); }
__device__ __forceinline__ unsigned rtn_bf16(unsigned u) {
    return (u + 0x7FFFu + ((u >> 16) & 1u)) >> 16;
}

// ---------------- one-time kernels ----------------

// fused: fp32->bf16 cast of P (8 floats/thread) + xq pack + degree count
__global__ __launch_bounds__(256) void k_prep(const float* __restrict__ Pf,
                                              unsigned short* __restrict__ Pbf,
                                              const float* __restrict__ xs0,
                                              const float* __restrict__ q,
                                              float2* __restrict__ xq,
                                              const int* __restrict__ edst,
                                              unsigned* __restrict__ deg) {
    size_t g = (size_t)blockIdx.x * 256 + threadIdx.x;
    size_t idx = g * 8;
    float4 a = *(const float4*)(Pf + idx);
    float4 c = *(const float4*)(Pf + idx + 4);
    uint4 o;
    o.x = rtn_bf16(__float_as_uint(a.x)) | (rtn_bf16(__float_as_uint(a.y)) << 16);
    o.y = rtn_bf16(__float_as_uint(a.z)) | (rtn_bf16(__float_as_uint(a.w)) << 16);
    o.z = rtn_bf16(__float_as_uint(c.x)) | (rtn_bf16(__float_as_uint(c.y)) << 16);
    o.w = rtn_bf16(__float_as_uint(c.z)) | (rtn_bf16(__float_as_uint(c.w)) << 16);
    *(uint4*)(Pbf + idx) = o;
    if (g < NN) { float2 v; v.x = xs0[g]; v.y = q[g]; xq[g] = v; }
    if (g < EE) atomicAdd(&deg[edst[g]], 1u);
}

__global__ void k_bsum(const unsigned* __restrict__ deg, unsigned* __restrict__ bsum) {
    __shared__ unsigned r[256];
    int t = threadIdx.x;
    r[t] = deg[blockIdx.x * 256 + t];
    __syncthreads();
    for (int o = 128; o > 0; o >>= 1) { if (t < o) r[t] += r[t + o]; __syncthreads(); }
    if (t == 0) bsum[blockIdx.x] = r[0];
}

__global__ void k_scanb(const unsigned* __restrict__ bsum, unsigned* __restrict__ bbase) {
    __shared__ unsigned r[512];
    int t = threadIdx.x;
    unsigned own = bsum[t];
    r[t] = own;
    __syncthreads();
    for (int o = 1; o < 512; o <<= 1) {
        unsigned v = (t >= o) ? r[t - o] : 0u;
        __syncthreads();
        r[t] += v;
        __syncthreads();
    }
    bbase[t] = r[t] - own;
}

__global__ void k_offsets(const unsigned* __restrict__ deg, const unsigned* __restrict__ bbase,
                          unsigned* __restrict__ rowstart, unsigned* __restrict__ cursor) {
    __shared__ unsigned r[256];
    int t = threadIdx.x;
    int i = blockIdx.x * 256 + t;
    unsigned d = deg[i];
    r[t] = d;
    __syncthreads();
    for (int o = 1; o < 256; o <<= 1) {
        unsigned v = (t >= o) ? r[t - o] : 0u;
        __syncthreads();
        r[t] += v;
        __syncthreads();
    }
    unsigned excl = r[t] - d + bbase[blockIdx.x];
    rowstart[i] = excl;
    cursor[i] = excl;
}

__global__ void k_fill(const int* __restrict__ src, const int* __restrict__ dst,
                       unsigned* __restrict__ cursor, int* __restrict__ csr_src) {
    int e = blockIdx.x * blockDim.x + threadIdx.x;
    unsigned pos = atomicAdd(&cursor[dst[e]], 1u);
    csr_src[pos] = src[e];
}

// ---------------- per-step kernels ----------------

// fused gather + node MLP (unchanged, proven)
__global__ void k_node_g(const float2* __restrict__ xq,
                         const float* __restrict__ Win, const float* __restrict__ bin,
                         const unsigned* __restrict__ rowstart, const unsigned* __restrict__ deg,
                         const int* __restrict__ csr_src,
                         const float* __restrict__ Wmsg, const float* __restrict__ bmsg,
                         const float* __restrict__ Wout, const float* __restrict__ bout,
                         float* __restrict__ pred, float* __restrict__ out_preds, int step) {
    int tid = threadIdx.x;                  // 256 = 8 nodes x 32 channels
    int d = tid & 31;
    int i = blockIdx.x * 8 + (tid >> 5);
    float w0 = Win[d], w1 = Win[DD + d], b0 = bin[d];
    float wcol[DD];
    #pragma unroll
    for (int k = 0; k < DD; ++k) wcol[k] = Wmsg[k * DD + d];
    unsigned rs = rowstart[i];
    unsigned dg = deg[i];
    unsigned nfull = dg < 32u ? dg : 32u;
    float xv = 0.f, qv = 0.f;
    if ((unsigned)d < nfull) {
        int sv = csr_src[rs + d];
        float2 v = xq[sv];
        xv = v.x; qv = v.y;
    }
    float s = 0.f;
    for (unsigned j = 0; j < nfull; ++j) {
        float xj = __shfl(xv, (int)j, 32);
        float qj = __shfl(qv, (int)j, 32);
        s += fmaxf(xj * w0 + qj * w1 + b0, 0.f);
    }
    for (unsigned j = 32; j < dg; ++j) {
        int sv = csr_src[rs + j];
        float2 v = xq[sv];
        s += fmaxf(v.x * w0 + v.y * w1 + b0, 0.f);
    }
    float2 self = xq[i];
    float hval = fmaxf(self.x * w0 + self.y * w1 + b0, 0.f);
    float agg = (float)dg * bmsg[d];
    #pragma unroll
    for (int k = 0; k < DD; ++k) agg += __shfl(s, k, 32) * wcol[k];
    float h2 = fmaxf(hval + agg, 0.f);
    float v = h2 * Wout[d];
    for (int o = 16; o > 0; o >>= 1) v += __shfl_down(v, o, 32);
    if (d == 0) {
        float pr = v + bout[0];
        pred[i] = pr;
        out_preds[i * NSTEPS + step] = pr;
    }
}

// fused labels + dd + df partial: 2048 blocks (8/CU), 256 threads = 4 waves.
// block = (graph b, 64-row slab s). Sr/Sp computed redundantly per block
// (6KB L2-hot reads). Slab-0 block writes labels. df accumulated via atomics
// (8 writers per address).
__global__ __launch_bounds__(256) void k_dfc(const unsigned short* __restrict__ Pbf,
                                             const float2* __restrict__ xq,
                                             const float* __restrict__ xsol,
                                             const float* __restrict__ pred,
                                             float* __restrict__ out_labels,
                                             float* __restrict__ df,
                                             float tau, int step) {
    __shared__ float dd_l[64];
    __shared__ float sl[4 * FF];
    __shared__ float redA[4], redB[4];
    int blk = blockIdx.x;
    int b = blk >> 3, s = blk & 7;
    int t = threadIdx.x;
    int w = t >> 6, lane = t & 63;
    int gbase = b * NPER;

    // --- graph-wide Sr, Sp (rows t and t+256) ---
    float x0 = xq[gbase + t].x;
    float x1 = xq[gbase + 256 + t].x;
    float r0 = xsol[gbase + t] - x0;
    float r1 = xsol[gbase + 256 + t] - x1;
    float a1 = fabsf(r0) + fabsf(r1);
    float a2 = fabsf(pred[gbase + t]) + fabsf(pred[gbase + 256 + t]);
    #pragma unroll
    for (int o = 32; o > 0; o >>= 1) {
        a1 += __shfl_down(a1, o, 64);
        a2 += __shfl_down(a2, o, 64);
    }
    if (lane == 0) { redA[w] = a1; redB[w] = a2; }
    __syncthreads();
    float Sr = 1e-12f + redA[0] + redA[1] + redA[2] + redA[3];
    float Sp = 1e-12f + redB[0] + redB[1] + redB[2] + redB[3];
    if (s == 0) {
        out_labels[(size_t)(gbase + t) * NSTEPS + step] = r0 / Sr;
        out_labels[(size_t)(gbase + 256 + t) * NSTEPS + step] = r1 / Sr;
    }
    if (t < 64) {
        int row = s * 64 + t;
        float xx = xq[gbase + row].x;
        dd_l[t] = pred[gbase + row] / Sp + 3.0f * tau / (xx + tau);
    }
    __syncthreads();

    // --- stream P slab: wave w rows s*64 + w*16 .. +15, lane l chans 4l..4l+3
    size_t pbase = ((size_t)(gbase + s * 64 + w * 16)) * FF + 4 * lane;
    const uint2* Pr = (const uint2*)(Pbf + pbase);
    float4 acc = {0.f, 0.f, 0.f, 0.f};
    #pragma unroll
    for (int n = 0; n < 16; ++n) {
        uint2 pv = Pr[(size_t)n * 64];     // row stride = 64 uint2 = 256 bf16
        float sc = dd_l[w * 16 + n];
        acc.x += bflo(pv.x) * sc; acc.y += bfhi(pv.x) * sc;
        acc.z += bflo(pv.y) * sc; acc.w += bfhi(pv.y) * sc;
    }
    ((float4*)sl)[w * 64 + lane] = acc;
    __syncthreads();
    if (t < FF) {
        float v = sl[t] + sl[FF + t] + sl[2 * FF + t] + sl[3 * FF + t];
        atomicAdd(&df[(size_t)(step * BB + b) * FF + t], v);
    }
}

// fused pproj + line-search + update (+ final-step labels): one block per graph,
// 1024 threads = 16 waves, wave w rows w*32..+31, block-local min (no atomics).
__global__ __launch_bounds__(1024) void k_ppu(const unsigned short* __restrict__ Pbf,
                                              const float* __restrict__ df,
                                              float2* __restrict__ xq,
                                              const float* __restrict__ xsol,
                                              float* __restrict__ out_labels,
                                              int step, int last) {
    __shared__ float x_l[NPER], pp_l[NPER], dfl[FF];
    __shared__ float wmin[16], red[16];
    int b = blockIdx.x;
    int t = threadIdx.x;
    int w = t >> 6, lane = t & 63;
    int gbase = b * NPER;
    if (t < FF) dfl[t] = df[(size_t)(step * BB + b) * FF + t];
    if (t < NPER) x_l[t] = xq[gbase + t].x;
    __syncthreads();

    float4 dfv = ((const float4*)dfl)[lane];         // chans 4l..4l+3
    const uint2* Pr = (const uint2*)(Pbf + ((size_t)(gbase + w * 32)) * FF + 4 * lane);
    float mloc = 5.0f;
    #pragma unroll
    for (int n = 0; n < 32; ++n) {
        uint2 pv = Pr[(size_t)n * 64];
        float pr = bflo(pv.x) * dfv.x + bfhi(pv.x) * dfv.y
                 + bflo(pv.y) * dfv.z + bfhi(pv.y) * dfv.w;
        #pragma unroll
        for (int o = 1; o < 64; o <<= 1) pr += __shfl_xor(pr, o, 64);
        int row = w * 32 + n;
        if (lane == 0) pp_l[row] = pr;
        float ratio = (pr < 0.f) ? (x_l[row] / fmaxf(-pr, 1e-12f)) : 5.0f;
        mloc = fminf(mloc, ratio);
    }
    if (lane == 0) wmin[w] = mloc;
    __syncthreads();
    float mm = wmin[0];
    #pragma unroll
    for (int k = 1; k < 16; ++k) mm = fminf(mm, wmin[k]);
    float alpha = fminf(fmaxf(mm, 0.f), 5.0f) * 0.995f;
    float xnew = 0.f;
    if (t < NPER) {
        xnew = x_l[t] + alpha * pp_l[t];
        xq[gbase + t].x = xnew;
    }
    if (last) {
        // step-3 labels: r/Sr on the just-updated x
        float r = 0.f, a1 = 0.f;
        if (t < NPER) { r = xsol[gbase + t] - xnew; a1 = fabsf(r); }
        #pragma unroll
        for (int o = 32; o > 0; o >>= 1) a1 += __shfl_down(a1, o, 64);
        if (lane == 0) red[w] = a1;
        __syncthreads();
        float Sr = 1e-12f;
        #pragma unroll
        for (int k = 0; k < 16; ++k) Sr += red[k];
        if (t < NPER) out_labels[(size_t)(gbase + t) * NSTEPS + (NSTEPS - 1)] = r / Sr;
    }
}

// ---------------- launch ----------------

extern "C" void kernel_launch(void* const* d_in, const int* in_sizes, int n_in,
                              void* d_out, int out_size, void* d_ws, size_t ws_size,
                              hipStream_t stream) {
    const float* x_start = (const float*)d_in[0];
    const float* x_sol   = (const float*)d_in[1];
    const float* q       = (const float*)d_in[2];
    const float* P       = (const float*)d_in[3];
    const float* Win     = (const float*)d_in[4];
    const float* bin     = (const float*)d_in[5];
    const float* Wmsg    = (const float*)d_in[6];
    const float* bmsg    = (const float*)d_in[7];
    const float* Wout    = (const float*)d_in[8];
    const float* bout    = (const float*)d_in[9];
    const int*   esrc    = (const int*)d_in[10];
    const int*   edst    = (const int*)d_in[11];
    // d_in[12] vals_batch unused: batch(i) == i >> 9 (equal-sized contiguous graphs)

    float* out_preds  = (float*)d_out;                // [N, 4] row-major
    float* out_labels = (float*)d_out + (size_t)NN * NSTEPS;

    float* w = (float*)d_ws;
    unsigned* deg = (unsigned*)w;      w += NN;          // |
    float* df     = w;                 w += (size_t)3 * BB * FF;   // | one memset covers both
    float2* xq  = (float2*)w; w += 2 * (size_t)NN;
    float* pred  = w; w += NN;
    unsigned* rowstart = (unsigned*)w; w += NN;
    unsigned* cursor   = (unsigned*)w; w += NN;
    unsigned* bsum     = (unsigned*)w; w += NN / 256;   // 512
    unsigned* bbase    = (unsigned*)w; w += NN / 256;   // 512
    int* csr_src       = (int*)w;      w += EE;
    unsigned short* Pbf = (unsigned short*)w;           // 64 MB bf16 copy of P

    // --- one-time: zero deg+df, fused prep (cast+pack+deg), CSR build
    hipMemsetAsync(deg, 0, (NN + (size_t)3 * BB * FF) * sizeof(unsigned), stream);
    k_prep<<<(NN / 256) * (FF / 8), 256, 0, stream>>>(P, Pbf, x_start, q, xq, edst, deg);
    k_bsum<<<NN / 256, 256, 0, stream>>>(deg, bsum);
    k_scanb<<<1, NN / 256, 0, stream>>>(bsum, bbase);
    k_offsets<<<NN / 256, 256, 0, stream>>>(deg, bbase, rowstart, cursor);
    k_fill<<<EE / 256, 256, 0, stream>>>(esrc, edst, cursor, csr_src);

    float tau = 0.1f;
    for (int step = 0; step < NSTEPS; ++step) {
        k_node_g<<<NN / 8, 256, 0, stream>>>(xq, Win, bin, rowstart, deg, csr_src,
                                             Wmsg, bmsg, Wout, bout, pred, out_preds, step);
        if (step < NSTEPS - 1) {
            k_dfc<<<BB * 8, 256, 0, stream>>>(Pbf, xq, x_sol, pred, out_labels, df, tau, step);
            k_ppu<<<BB, 1024, 0, stream>>>(Pbf, df, xq, x_sol, out_labels,
                                           step, step == NSTEPS - 2 ? 1 : 0);
        }
        tau = fmaxf(tau * 0.5f, 1e-5f);
    }
}